// Round 7
// baseline (187.730 us; speedup 1.0000x reference)
//
#include <hip/hip_runtime.h>
#include <cstdint>
#include <cstddef>

// ---------- types ----------
typedef __bf16 bf16;
typedef __attribute__((ext_vector_type(8))) __bf16 bf16x8;
typedef __attribute__((ext_vector_type(4))) float f32x4;
typedef __attribute__((ext_vector_type(16))) float f32x16;

#define MFMA16(a, b, c) __builtin_amdgcn_mfma_f32_16x16x32_bf16((a), (b), (c), 0, 0, 0)
#define MFMA32(a, b, c) __builtin_amdgcn_mfma_f32_32x32x16_bf16((a), (b), (c), 0, 0, 0)

// Problem constants (B=2, S=2048, HIDDEN=1024, H=16, D=64)
static constexpr int BB   = 2;
static constexpr int SS   = 2048;
static constexpr int HID  = 1024;
static constexpr int NH   = 16;
static constexpr int HD   = 64;
static constexpr int MROW = BB * SS;     // 4096
static constexpr int NQKV = 3 * HID;     // 3072
static constexpr float LOG2E = 1.4426950408889634f;
static constexpr float MSHIFT = 16.0f;   // static softmax shift (log2 domain)

__device__ __forceinline__ uint32_t pack_bf16(float a, float b) {
    union { bf16 h[2]; uint32_t u; } x;
    x.h[0] = (bf16)a; x.h[1] = (bf16)b;
    return x.u;
}

__device__ __forceinline__ uint32_t pack_raw(bf16 a, bf16 b) {
    union { bf16 h[2]; uint32_t u; } x;
    x.h[0] = a; x.h[1] = b;
    return x.u;
}

__device__ __forceinline__ float exp2i(float x) {
    float r; asm("v_exp_f32 %0, %1" : "=v"(r) : "v"(x)); return r;
}

// v_permlane32_swap_b32: a' = [a.lo | b.lo], b' = [a.hi | b.hi]
__device__ __forceinline__ void plswap(uint32_t& a, uint32_t& b) {
    asm("v_permlane32_swap_b32 %0, %1" : "+v"(a), "+v"(b));
}

// async global->LDS, 16B per lane (GEMM staging)
__device__ __forceinline__ void gload16(const void* g, void* l) {
    __builtin_amdgcn_global_load_lds(
        (const __attribute__((address_space(1))) void*)g,
        (__attribute__((address_space(3))) void*)l, 16, 0, 0);
}

// ---------- kernel 1: fp32 -> bf16 convert ----------
__global__ __launch_bounds__(256) void cvt_hidden(const float* __restrict__ in,
                                                  bf16* __restrict__ out) {
    const int i = (blockIdx.x * 256 + threadIdx.x) * 8;
    float4 f0 = *(const float4*)&in[i];
    float4 f1 = *(const float4*)&in[i + 4];
    bf16x8 o;
    o[0] = (bf16)f0.x; o[1] = (bf16)f0.y; o[2] = (bf16)f0.z; o[3] = (bf16)f0.w;
    o[4] = (bf16)f1.x; o[5] = (bf16)f1.y; o[6] = (bf16)f1.z; o[7] = (bf16)f1.w;
    *(bf16x8*)&out[i] = o;
}

// ---------- kernel 1b: mask * log2e - MSHIFT ----------
__global__ __launch_bounds__(256) void maskcvt(const float* __restrict__ m,
                                               float* __restrict__ o) {
    const int i = blockIdx.x * 256 + threadIdx.x;
    o[i] = m[i] * LOG2E - MSHIFT;
}

// ---------- kernel 2: transpose-convert W -> Wt [n][k] bf16 ----------
__global__ __launch_bounds__(256) void wtrans(const float* __restrict__ Wq,
                                              const float* __restrict__ Wk,
                                              const float* __restrict__ Wv,
                                              bf16* __restrict__ Wt) {
    __shared__ float tile[32][33];
    const float* W = (blockIdx.z == 0) ? Wq : (blockIdx.z == 1) ? Wk : Wv;
    bf16* O = Wt + (size_t)blockIdx.z * HID * HID;
    const int x  = blockIdx.x * 32 + threadIdx.x;
    const int y0 = blockIdx.y * 32;
#pragma unroll
    for (int i = threadIdx.y; i < 32; i += 8)
        tile[i][threadIdx.x] = W[(size_t)(y0 + i) * HID + x];
    __syncthreads();
    const int k = y0 + threadIdx.x;
#pragma unroll
    for (int i = threadIdx.y; i < 32; i += 8)
        O[(size_t)(blockIdx.x * 32 + i) * HID + k] = (bf16)tile[threadIdx.x][i];
}

// ---------- kernel 3: QKV GEMM (global_load_lds staging; unchanged) ----------
__global__ __launch_bounds__(256) void qkv_gemm(
    const bf16* __restrict__ A, const bf16* __restrict__ Bt,
    const float* __restrict__ bq, const float* __restrict__ bk,
    const float* __restrict__ bv,
    bf16* __restrict__ Qo, bf16* __restrict__ Ko, bf16* __restrict__ Vo) {
    __shared__ __align__(16) bf16 As[128 * 32];
    __shared__ __align__(16) bf16 Bs[128 * 32];
    const int t = threadIdx.x, l = t & 63;
    const int l15 = l & 15, l4 = l >> 4;
    const int w = t >> 6;
    const int wm = w >> 1, wn = w & 1;
    const int m0 = blockIdx.y * 128, n0 = blockIdx.x * 128;

    f32x4 acc[4][4] = {};

    for (int kt = 0; kt < 32; ++kt) {
        const int k0 = kt * 32;
        __syncthreads();
#pragma unroll
        for (int cc = 0; cc < 2; ++cc) {
            const int c = t + cc * 256;
            const int row = c >> 2, col = (c & 3) * 8;
            gload16(&A[(size_t)(m0 + row) * HID + k0 + col], (char*)As + c * 16);
            gload16(&Bt[(size_t)(n0 + row) * HID + k0 + col], (char*)Bs + c * 16);
        }
        __syncthreads();

        bf16x8 af[4], bf_[4];
#pragma unroll
        for (int mi = 0; mi < 4; ++mi) {
            const int r = wm * 64 + mi * 16 + l15;
            af[mi] = *(const bf16x8*)((const char*)As + r * 64 + l4 * 16);
        }
#pragma unroll
        for (int ni = 0; ni < 4; ++ni) {
            const int r = wn * 64 + ni * 16 + l15;
            bf_[ni] = *(const bf16x8*)((const char*)Bs + r * 64 + l4 * 16);
        }
        __builtin_amdgcn_s_setprio(1);
#pragma unroll
        for (int mi = 0; mi < 4; ++mi)
#pragma unroll
            for (int ni = 0; ni < 4; ++ni)
                acc[mi][ni] = MFMA16(af[mi], bf_[ni], acc[mi][ni]);
        __builtin_amdgcn_s_setprio(0);
    }

#pragma unroll
    for (int mi = 0; mi < 4; ++mi) {
#pragma unroll
        for (int ni = 0; ni < 4; ++ni) {
            const int ng = n0 + wn * 64 + ni * 16 + l15;
            const int qkv = ng >> 10;
            const int nn = ng & 1023;
            const int hh = nn >> 6, dd = nn & 63;
            const float* bp = (qkv == 0) ? bq : (qkv == 1) ? bk : bv;
            bf16* op = (qkv == 0) ? Qo : (qkv == 1) ? Ko : Vo;
            const float bias = bp[nn];
            const float scl = (qkv == 0) ? 0.125f * LOG2E : 1.0f;
            const int mg = m0 + wm * 64 + mi * 16 + l4 * 4;
            const int bb = mg >> 11, ss = mg & 2047;
            bf16* dst = op + ((size_t)(bb * NH + hh) * SS + ss) * HD + dd;
#pragma unroll
            for (int j = 0; j < 4; ++j)
                dst[(size_t)j * HD] = (bf16)((acc[mi][ni][j] + bias) * scl);
        }
    }
}

// ---------- kernel 4: flash attention v7 — BARRIER-FREE key-partitioned ----------
// Block = 32 queries, 4 waves partition keys (wave w: keys kt*128 + w*32).
// K: straight global->reg A-frags (no LDS). V^T: wave-private 4KB LDS,
// single-buffered (per-wave DS ordering => no barrier). Static-shift softmax
// => partial merge is pure addition. ZERO __syncthreads in the K-loop;
// 2 barriers at the end for the cross-wave O/l merge. Direct out write.
__global__ __launch_bounds__(256) void attn_fwd(
    const bf16* __restrict__ Q, const bf16* __restrict__ K,
    const bf16* __restrict__ V, const float* __restrict__ mkl,
    float* __restrict__ out) {
    __shared__ __align__(16) char smem[34816];   // V^T (4x4KB) then merge area

    const int t = threadIdx.x, l = t & 63, w = t >> 6;
    const int l31 = l & 31, h = l >> 5;

    const int bid = blockIdx.x;
    const int nid = (bid & 7) * 256 + (bid >> 3);   // 2048 = 8*256 bijective
    const int bh = nid >> 6, qb = nid & 63;
    const int b = bh >> 4, hh = bh & 15;
    const int q0 = qb * 32;

    const bf16* Qp = Q + (size_t)bh * SS * HD;
    const bf16* Kp = K + (size_t)bh * SS * HD;
    const bf16* Vp = V + (size_t)bh * SS * HD;
    const float* mkp = mkl + b * SS;

    char* Vt = smem + w * 4096;      // wave-private V^T: 64 rows x 64B

    // Q frags (B-operand): lane q = l31, d = c*16 + h*8 + e
    bf16x8 qf[4];
#pragma unroll
    for (int c = 0; c < 4; ++c)
        qf[c] = *(const bf16x8*)&Qp[(size_t)(q0 + l31) * HD + c * 16 + h * 8];

    // V staging: lane owns key-pair vp (keys 2vp,2vp+1) x two 8-d blocks
    const int vp = l & 15;
    const int du0 = (l >> 4) * 16;   // d-blocks du0 and du0+8

#define VSTORE(va, vb, db)                                                   \
    _Pragma("unroll")                                                        \
    for (int i = 0; i < 8; ++i) {                                            \
        const int d_ = (db) + i;                                             \
        *(uint32_t*)(Vt + d_ * 64 +                                          \
                     (((vp >> 2) ^ ((d_ ^ (d_ >> 2)) & 3)) * 16) +           \
                     (vp & 3) * 4) = pack_raw((va)[i], (vb)[i]);             \
    }

    float lrun = 0.f;
    f32x16 o0 = {}, o1 = {};   // O^T partial: rows d / d+32, col q = l31

    // ---- prologue: stage V^T for tile 0 (wave-private, no barrier) ----
    {
        const int kv = w * 32;
        bf16x8 va0 = *(const bf16x8*)&Vp[(size_t)(kv + 2 * vp) * HD + du0];
        bf16x8 vb0 = *(const bf16x8*)&Vp[(size_t)(kv + 2 * vp + 1) * HD + du0];
        bf16x8 va1 = *(const bf16x8*)&Vp[(size_t)(kv + 2 * vp) * HD + du0 + 8];
        bf16x8 vb1 = *(const bf16x8*)&Vp[(size_t)(kv + 2 * vp + 1) * HD + du0 + 8];
        VSTORE(va0, vb0, du0)
        VSTORE(va1, vb1, du0 + 8)
    }

    for (int kt = 0; kt < 16; ++kt) {
        const int key0 = kt * 128 + w * 32;
        // ---- K A-frags straight from global (contiguous 16B per lane) ----
        bf16x8 kf[4];
#pragma unroll
        for (int c = 0; c < 4; ++c)
            kf[c] = *(const bf16x8*)&Kp[(size_t)(key0 + l31) * HD + c * 16 + h * 8];
        // ---- issue next tile's V loads (stay in flight under compute) ----
        const int kvn = (kt == 15 ? 15 : kt + 1) * 128 + w * 32;
        bf16x8 va0 = *(const bf16x8*)&Vp[(size_t)(kvn + 2 * vp) * HD + du0];
        bf16x8 vb0 = *(const bf16x8*)&Vp[(size_t)(kvn + 2 * vp + 1) * HD + du0];
        bf16x8 va1 = *(const bf16x8*)&Vp[(size_t)(kvn + 2 * vp) * HD + du0 + 8];
        bf16x8 vb1 = *(const bf16x8*)&Vp[(size_t)(kvn + 2 * vp + 1) * HD + du0 + 8];

        // ---- S^T = K Q^T (log2 domain) ----
        f32x16 st = {};
        __builtin_amdgcn_s_setprio(1);
#pragma unroll
        for (int c = 0; c < 4; ++c) st = MFMA32(kf[c], qf[c], st);
        __builtin_amdgcn_s_setprio(0);

        // ---- static-shift softmax: p = 2^(st + mask') ----
        float ps = 0.f;
#pragma unroll
        for (int rq = 0; rq < 4; ++rq) {
            const f32x4 mk = *(const f32x4*)&mkp[key0 + rq * 8 + 4 * h];
#pragma unroll
            for (int j = 0; j < 4; ++j) {
                const float p = exp2i(st[rq * 4 + j] + mk[j]);
                st[rq * 4 + j] = p;
                ps += p;
            }
        }
        lrun += ps;

        // ---- P frags (pack + permlane32_swap) and PV accumulate ----
#pragma unroll
        for (int cc = 0; cc < 2; ++cc) {
            uint32_t wA = pack_bf16(st[8 * cc + 0], st[8 * cc + 1]);
            uint32_t wB = pack_bf16(st[8 * cc + 2], st[8 * cc + 3]);
            uint32_t wC = pack_bf16(st[8 * cc + 4], st[8 * cc + 5]);
            uint32_t wD = pack_bf16(st[8 * cc + 6], st[8 * cc + 7]);
            plswap(wA, wC);
            plswap(wB, wD);
            union { uint32_t u[4]; bf16x8 v; } pb;
            pb.u[0] = wA; pb.u[1] = wB; pb.u[2] = wC; pb.u[3] = wD;
            const int d0_ = l31, d1_ = 32 + l31;
            const int s0 = (((cc * 2 + h) ^ ((d0_ ^ (d0_ >> 2)) & 3)) * 16);
            const int s1 = (((cc * 2 + h) ^ ((d1_ ^ (d1_ >> 2)) & 3)) * 16);
            __builtin_amdgcn_s_setprio(1);
            {
                bf16x8 vf0 = *(const bf16x8*)(Vt + d0_ * 64 + s0);
                o0 = MFMA32(vf0, pb.v, o0);
                bf16x8 vf1 = *(const bf16x8*)(Vt + d1_ * 64 + s1);
                o1 = MFMA32(vf1, pb.v, o1);
            }
            __builtin_amdgcn_s_setprio(0);
        }

        // ---- write next V^T (after PV reads; per-wave DS order => safe) ----
        VSTORE(va0, vb0, du0)
        VSTORE(va1, vb1, du0 + 8)
    }

    // ---- cross-wave merge (the only 2 barriers in the kernel) ----
    lrun += __shfl_xor(lrun, 32);
    __syncthreads();                         // all waves done with V^T region
    float* Om  = (float*)smem;               // [4][64][33] f32 = 33792 B
    float* lml = (float*)(smem + 33792);     // [4][32]
#pragma unroll
    for (int r = 0; r < 16; ++r) {
        const int d = (r & 3) + 8 * (r >> 2) + 4 * h;
        Om[(w * 64 + d) * 33 + l31] = o0[r];
        Om[(w * 64 + d + 32) * 33 + l31] = o1[r];
    }
    if (l < 32) lml[w * 32 + l] = lrun;
    __syncthreads();

    const int mq = t >> 3, dg = (t & 7) * 8;
    const float lsum = lml[mq] + lml[32 + mq] + lml[64 + mq] + lml[96 + mq];
    const float inv = 1.0f / lsum;
    float r8[8];
#pragma unroll
    for (int i = 0; i < 8; ++i) {
        const int d = dg + i;
        r8[i] = (Om[d * 33 + mq] + Om[(64 + d) * 33 + mq] +
                 Om[(128 + d) * 33 + mq] + Om[(192 + d) * 33 + mq]) * inv;
    }
    float* op = &out[((size_t)(b * SS + q0 + mq)) * HID + hh * HD + dg];
    f32x4 w0, w1;
#pragma unroll
    for (int i = 0; i < 4; ++i) { w0[i] = r8[i]; w1[i] = r8[4 + i]; }
    *(f32x4*)op = w0;
    *(f32x4*)(op + 4) = w1;
#undef VSTORE
}

// ---------- launch ----------
extern "C" void kernel_launch(void* const* d_in, const int* in_sizes, int n_in,
                              void* d_out, int out_size, void* d_ws, size_t ws_size,
                              hipStream_t stream) {
    (void)in_sizes; (void)n_in; (void)out_size; (void)ws_size;
    const float* hs  = (const float*)d_in[0];
    const float* msk = (const float*)d_in[1];
    const float* Wq  = (const float*)d_in[2];
    const float* bq  = (const float*)d_in[3];
    const float* Wk  = (const float*)d_in[4];
    const float* bk  = (const float*)d_in[5];
    const float* Wv  = (const float*)d_in[6];
    const float* bv  = (const float*)d_in[7];
    float* out = (float*)d_out;
    char* ws = (char*)d_ws;
    const size_t MB = 1 << 20;

    bf16* Qb  = (bf16*)ws;                    // 0..8MB   [B,H,S,D]
    bf16* Kb  = (bf16*)(ws + 8 * MB);         // 8..16
    bf16* Vb  = (bf16*)(ws + 16 * MB);        // 16..24
    float* mk2 = (float*)(ws + 24 * MB);      // 24MB + 16KB
    bf16* Xb  = (bf16*)(ws + 25 * MB);        // 25..33
    bf16* Wt  = (bf16*)(ws + 33 * MB);        // 33..39

    cvt_hidden<<<dim3(MROW * HID / (256 * 8)), dim3(256), 0, stream>>>(hs, Xb);
    maskcvt<<<dim3(BB * SS / 256), dim3(256), 0, stream>>>(msk, mk2);
    wtrans<<<dim3(32, 32, 3), dim3(32, 8), 0, stream>>>(Wq, Wk, Wv, Wt);
    qkv_gemm<<<dim3(NQKV / 128, MROW / 128), dim3(256), 0, stream>>>(
        Xb, Wt, bq, bk, bv, Qb, Kb, Vb);
    attn_fwd<<<dim3(2048), dim3(256), 0, stream>>>(Qb, Kb, Vb, mk2, out);
}

// Round 8
// 157.133 us; speedup vs baseline: 1.1947x; 1.1947x over previous
//
#include <hip/hip_runtime.h>
#include <cstdint>
#include <cstddef>

// ---------- types ----------
typedef __bf16 bf16;
typedef __attribute__((ext_vector_type(8))) __bf16 bf16x8;
typedef __attribute__((ext_vector_type(4))) float f32x4;
typedef __attribute__((ext_vector_type(16))) float f32x16;

#define MFMA16(a, b, c) __builtin_amdgcn_mfma_f32_16x16x32_bf16((a), (b), (c), 0, 0, 0)
#define MFMA32(a, b, c) __builtin_amdgcn_mfma_f32_32x32x16_bf16((a), (b), (c), 0, 0, 0)

// Problem constants (B=2, S=2048, HIDDEN=1024, H=16, D=64)
static constexpr int BB   = 2;
static constexpr int SS   = 2048;
static constexpr int HID  = 1024;
static constexpr int NH   = 16;
static constexpr int HD   = 64;
static constexpr int MROW = BB * SS;     // 4096
static constexpr int NQKV = 3 * HID;     // 3072
static constexpr float LOG2E = 1.4426950408889634f;
static constexpr float MSHIFT = 16.0f;   // static softmax shift (log2 domain)

// XOR swizzle on 16B slots
__device__ __forceinline__ int SW(int r) { return ((r ^ (r >> 3)) & 7) << 4; }

__device__ __forceinline__ uint32_t pack_bf16(float a, float b) {
    union { bf16 h[2]; uint32_t u; } x;
    x.h[0] = (bf16)a; x.h[1] = (bf16)b;
    return x.u;
}

__device__ __forceinline__ uint32_t pack_raw(bf16 a, bf16 b) {
    union { bf16 h[2]; uint32_t u; } x;
    x.h[0] = a; x.h[1] = b;
    return x.u;
}

__device__ __forceinline__ float exp2i(float x) {
    float r; asm("v_exp_f32 %0, %1" : "=v"(r) : "v"(x)); return r;
}

// v_permlane32_swap_b32: a' = [a.lo | b.lo], b' = [a.hi | b.hi]
__device__ __forceinline__ void plswap(uint32_t& a, uint32_t& b) {
    asm("v_permlane32_swap_b32 %0, %1" : "+v"(a), "+v"(b));
}

// async global->LDS, 16B per lane
__device__ __forceinline__ void gload16(const void* g, void* l) {
    __builtin_amdgcn_global_load_lds(
        (const __attribute__((address_space(1))) void*)g,
        (__attribute__((address_space(3))) void*)l, 16, 0, 0);
}

// ---------- kernel 1: fp32 -> bf16 convert ----------
__global__ __launch_bounds__(256) void cvt_hidden(const float* __restrict__ in,
                                                  bf16* __restrict__ out) {
    const int i = (blockIdx.x * 256 + threadIdx.x) * 8;
    float4 f0 = *(const float4*)&in[i];
    float4 f1 = *(const float4*)&in[i + 4];
    bf16x8 o;
    o[0] = (bf16)f0.x; o[1] = (bf16)f0.y; o[2] = (bf16)f0.z; o[3] = (bf16)f0.w;
    o[4] = (bf16)f1.x; o[5] = (bf16)f1.y; o[6] = (bf16)f1.z; o[7] = (bf16)f1.w;
    *(bf16x8*)&out[i] = o;
}

// ---------- kernel 1b: mask * log2e - MSHIFT ----------
__global__ __launch_bounds__(256) void maskcvt(const float* __restrict__ m,
                                               float* __restrict__ o) {
    const int i = blockIdx.x * 256 + threadIdx.x;
    o[i] = m[i] * LOG2E - MSHIFT;
}

// ---------- kernel 2: transpose-convert W -> Wt [n][k] bf16 ----------
__global__ __launch_bounds__(256) void wtrans(const float* __restrict__ Wq,
                                              const float* __restrict__ Wk,
                                              const float* __restrict__ Wv,
                                              bf16* __restrict__ Wt) {
    __shared__ float tile[32][33];
    const float* W = (blockIdx.z == 0) ? Wq : (blockIdx.z == 1) ? Wk : Wv;
    bf16* O = Wt + (size_t)blockIdx.z * HID * HID;
    const int x  = blockIdx.x * 32 + threadIdx.x;
    const int y0 = blockIdx.y * 32;
#pragma unroll
    for (int i = threadIdx.y; i < 32; i += 8)
        tile[i][threadIdx.x] = W[(size_t)(y0 + i) * HID + x];
    __syncthreads();
    const int k = y0 + threadIdx.x;
#pragma unroll
    for (int i = threadIdx.y; i < 32; i += 8)
        O[(size_t)(blockIdx.x * 32 + i) * HID + k] = (bf16)tile[threadIdx.x][i];
}

// ---------- kernel 3: QKV GEMM (global_load_lds staging; unchanged) ----------
__global__ __launch_bounds__(256) void qkv_gemm(
    const bf16* __restrict__ A, const bf16* __restrict__ Bt,
    const float* __restrict__ bq, const float* __restrict__ bk,
    const float* __restrict__ bv,
    bf16* __restrict__ Qo, bf16* __restrict__ Ko, bf16* __restrict__ Vo) {
    __shared__ __align__(16) bf16 As[128 * 32];
    __shared__ __align__(16) bf16 Bs[128 * 32];
    const int t = threadIdx.x, l = t & 63;
    const int l15 = l & 15, l4 = l >> 4;
    const int w = t >> 6;
    const int wm = w >> 1, wn = w & 1;
    const int m0 = blockIdx.y * 128, n0 = blockIdx.x * 128;

    f32x4 acc[4][4] = {};

    for (int kt = 0; kt < 32; ++kt) {
        const int k0 = kt * 32;
        __syncthreads();
#pragma unroll
        for (int cc = 0; cc < 2; ++cc) {
            const int c = t + cc * 256;
            const int row = c >> 2, col = (c & 3) * 8;
            gload16(&A[(size_t)(m0 + row) * HID + k0 + col], (char*)As + c * 16);
            gload16(&Bt[(size_t)(n0 + row) * HID + k0 + col], (char*)Bs + c * 16);
        }
        __syncthreads();

        bf16x8 af[4], bf_[4];
#pragma unroll
        for (int mi = 0; mi < 4; ++mi) {
            const int r = wm * 64 + mi * 16 + l15;
            af[mi] = *(const bf16x8*)((const char*)As + r * 64 + l4 * 16);
        }
#pragma unroll
        for (int ni = 0; ni < 4; ++ni) {
            const int r = wn * 64 + ni * 16 + l15;
            bf_[ni] = *(const bf16x8*)((const char*)Bs + r * 64 + l4 * 16);
        }
        __builtin_amdgcn_s_setprio(1);
#pragma unroll
        for (int mi = 0; mi < 4; ++mi)
#pragma unroll
            for (int ni = 0; ni < 4; ++ni)
                acc[mi][ni] = MFMA16(af[mi], bf_[ni], acc[mi][ni]);
        __builtin_amdgcn_s_setprio(0);
    }

#pragma unroll
    for (int mi = 0; mi < 4; ++mi) {
#pragma unroll
        for (int ni = 0; ni < 4; ++ni) {
            const int ng = n0 + wn * 64 + ni * 16 + l15;
            const int qkv = ng >> 10;
            const int nn = ng & 1023;
            const int hh = nn >> 6, dd = nn & 63;
            const float* bp = (qkv == 0) ? bq : (qkv == 1) ? bk : bv;
            bf16* op = (qkv == 0) ? Qo : (qkv == 1) ? Ko : Vo;
            const float bias = bp[nn];
            const float scl = (qkv == 0) ? 0.125f * LOG2E : 1.0f;
            const int mg = m0 + wm * 64 + mi * 16 + l4 * 4;
            const int bb = mg >> 11, ss = mg & 2047;
            bf16* dst = op + ((size_t)(bb * NH + hh) * SS + ss) * HD + dd;
#pragma unroll
            for (int j = 0; j < 4; ++j)
                dst[(size_t)j * HD] = (bf16)((acc[mi][ni][j] + bias) * scl);
        }
    }
}

// ---------- kernel 4: flash attention v8 ----------
// R6 base + (a) DISTINCT __shared__ objects per buffer (alias-analysis: the
// t+1 prefetch DMA must not order against tile-t ds_reads), (b) 2-stage
// pipeline: QK^T(t+1) -> stB issued BEFORE softmax(t) on stA, so the MFMA
// pipe overlaps the VALU/trans softmax. Even/odd unroll, static buffers.
__global__ __launch_bounds__(256) void attn_fwd(
    const bf16* __restrict__ Q, const bf16* __restrict__ K,
    const bf16* __restrict__ V, const float* __restrict__ mkl,
    float* __restrict__ Op, float* __restrict__ ml) {
    __shared__ __align__(16) char Ks0[64 * 128];
    __shared__ __align__(16) char Ks1[64 * 128];
    __shared__ __align__(16) char Vt0[64 * 128];
    __shared__ __align__(16) char Vt1[64 * 128];

    const int t = threadIdx.x, l = t & 63, w = t >> 6;
    const int l31 = l & 31, h = l >> 5;

    const int bid = blockIdx.x;
    const int nid = (bid & 7) * 128 + (bid >> 3);   // 1024 = 8*128 bijective
    const int bh = nid >> 5, kh = (nid >> 4) & 1, qb = nid & 15;
    const int q0 = qb * 128 + w * 32;
    const int kbase = kh * (SS / 2);

    const bf16* Qp = Q + (size_t)bh * SS * HD;
    const bf16* Kp = K + (size_t)bh * SS * HD;
    const bf16* Vp = V + (size_t)bh * SS * HD;
    const float* mkp = mkl + (bh >> 4) * SS;

    // Q frags (B-operand): lane q = l31, d = c*16 + h*8 + e
    bf16x8 qf[4];
#pragma unroll
    for (int c = 0; c < 4; ++c)
        qf[c] = *(const bf16x8*)&Qp[(size_t)(q0 + l31) * HD + c * 16 + h * 8];

    float lrun = 0.f;
    f32x16 o0 = {}, o1 = {};   // O^T: rows d / d+32, col q = l31

    const int vp_ = t >> 3, vdb = (t & 7) * 8;
    const int krow_s = t >> 3, kcsw = ((t & 7) ^ ((krow_s ^ (krow_s >> 3)) & 7)) * 8;

    // ---- helpers as lambdas (compile-time buffer selection) ----
    auto stageK = [&](int tile, char* dst) {
        const int key0 = kbase + tile * 64;
#pragma unroll
        for (int cc = 0; cc < 2; ++cc) {
            const int c = t + cc * 256;
            const int row = c >> 3;
            const int csw = (c & 7) ^ ((row ^ (row >> 3)) & 7);
            gload16(&Kp[(size_t)(key0 + row) * HD + csw * 8], dst + c * 16);
        }
    };
    auto loadV = [&](int tile, bf16x8& va, bf16x8& vb) {
        const int key0 = kbase + tile * 64;
        va = *(const bf16x8*)&Vp[(size_t)(key0 + 2 * vp_) * HD + vdb];
        vb = *(const bf16x8*)&Vp[(size_t)(key0 + 2 * vp_ + 1) * HD + vdb];
    };
    auto storeV = [&](char* Vtn, const bf16x8& va, const bf16x8& vb) {
#pragma unroll
        for (int i = 0; i < 8; ++i) {
            const int d = vdb + i;
            *(uint32_t*)(Vtn + d * 128 + ((vp_ * 4) ^ SW(d))) =
                pack_raw(va[i], vb[i]);
        }
    };
    auto qkt = [&](const char* Ks, f32x16& st) {
        const int krow = l31;        // group-g rows handled via two halves below
        // two 32-key groups fused: rows g*32 + l31, g = 0,1 -> separate st?
        (void)krow; (void)Ks; (void)st;
    };
    (void)qkt;

    // ---- prologue ----
    stageK(0, Ks0);
    stageK(1, Ks1);
    {
        bf16x8 va, vb, vc, vd;
        loadV(0, va, vb);
        loadV(1, vc, vd);
        storeV(Vt0, va, vb);
        storeV(Vt1, vc, vd);
    }
    __syncthreads();   // Ks0/Ks1/Vt0/Vt1 ready

    // QK^T of tile 0 -> stA (two 32-key groups -> stA0, stA1)
    f32x16 stA0 = {}, stA1 = {}, stB0 = {}, stB1 = {};
    auto qk_tile = [&](const char* Ks, f32x16& s0, f32x16& s1) {
        __builtin_amdgcn_s_setprio(1);
#pragma unroll
        for (int c = 0; c < 4; ++c) {
            const int r0 = l31;
            bf16x8 kf0 = *(const bf16x8*)(Ks + r0 * 128 +
                                          ((c * 32 + h * 16) ^ SW(r0)));
            s0 = MFMA32(kf0, qf[c], s0);
        }
#pragma unroll
        for (int c = 0; c < 4; ++c) {
            const int r1 = 32 + l31;
            bf16x8 kf1 = *(const bf16x8*)(Ks + r1 * 128 +
                                          ((c * 32 + h * 16) ^ SW(r1)));
            s1 = MFMA32(kf1, qf[c], s1);
        }
        __builtin_amdgcn_s_setprio(0);
    };
    auto sm_pv = [&](f32x16& s0, f32x16& s1, const char* Vt, int tile) {
        const int key0 = kbase + tile * 64;
        // softmax (static shift): p = 2^(s + mask')
        float ps = 0.f;
#pragma unroll
        for (int g = 0; g < 2; ++g) {
            f32x16& st = g ? s1 : s0;
#pragma unroll
            for (int rq = 0; rq < 4; ++rq) {
                const f32x4 mk =
                    *(const f32x4*)&mkp[key0 + g * 32 + rq * 8 + 4 * h];
#pragma unroll
                for (int j = 0; j < 4; ++j) {
                    const float p = exp2i(st[rq * 4 + j] + mk[j]);
                    st[rq * 4 + j] = p;
                    ps += p;
                }
            }
        }
        lrun += ps;
        // P frags + PV
#pragma unroll
        for (int g = 0; g < 2; ++g) {
            f32x16& st = g ? s1 : s0;
#pragma unroll
            for (int cc = 0; cc < 2; ++cc) {
                uint32_t wA = pack_bf16(st[8 * cc + 0], st[8 * cc + 1]);
                uint32_t wB = pack_bf16(st[8 * cc + 2], st[8 * cc + 3]);
                uint32_t wC = pack_bf16(st[8 * cc + 4], st[8 * cc + 5]);
                uint32_t wD = pack_bf16(st[8 * cc + 6], st[8 * cc + 7]);
                plswap(wA, wC);
                plswap(wB, wD);
                union { uint32_t u[4]; bf16x8 v; } pb;
                pb.u[0] = wA; pb.u[1] = wB; pb.u[2] = wC; pb.u[3] = wD;
                const int colb = g * 64 + cc * 32 + h * 16;
                __builtin_amdgcn_s_setprio(1);
                {
                    bf16x8 vf0 = *(const bf16x8*)(Vt + l31 * 128 +
                                                  (colb ^ SW(l31)));
                    o0 = MFMA32(vf0, pb.v, o0);
                    const int r1 = 32 + l31;
                    bf16x8 vf1 = *(const bf16x8*)(Vt + r1 * 128 +
                                                  (colb ^ SW(r1)));
                    o1 = MFMA32(vf1, pb.v, o1);
                }
                __builtin_amdgcn_s_setprio(0);
            }
        }
        // zero for reuse as next accumulator
        s0 = f32x16{};
        s1 = f32x16{};
    };

    qk_tile(Ks0, stA0, stA1);
    __syncthreads();   // all waves done QK(0) before iter-0 overwrites Ks0

    constexpr int NT = (SS / 2) / 64;   // 16
#pragma unroll 1
    for (int ii = 0; ii < NT / 2; ++ii) {
        const int i0 = 2 * ii;          // even tile
        const bool more = (ii < NT / 2 - 1);
        // ===== even half: cur = stA (tile i0), next QK -> stB (tile i0+1) ==
        {
            bf16x8 va, vb;
            if (more) stageK(i0 + 2, Ks0);          // Ks0: tile i0's QK done
            loadV(i0 + 1, va, vb);
            qk_tile(Ks1, stB0, stB1);               // QK(i0+1)
            sm_pv(stA0, stA1, Vt0, i0);             // softmax+PV(i0)
            storeV(Vt1, va, vb);                    // V(i0+1) -> Vt1
            __syncthreads();
        }
        // ===== odd half: cur = stB (tile i0+1), next QK -> stA (i0+2) ======
        {
            bf16x8 va, vb;
            if (more) {
                stageK(i0 + 3, Ks1);
                loadV(i0 + 2, va, vb);
                qk_tile(Ks0, stA0, stA1);           // QK(i0+2)
            }
            sm_pv(stB0, stB1, Vt1, i0 + 1);         // softmax+PV(i0+1)
            if (more) storeV(Vt0, va, vb);          // V(i0+2) -> Vt0
            __syncthreads();
        }
    }

    // ---- epilogue: partials ----
    lrun += __shfl_xor(lrun, 32);
    const int part = kh * 512 + bh * 16 + qb;
    float* Ob = Op + (size_t)part * 8192;
    const int row = w * 32 + l31;
#pragma unroll
    for (int rq = 0; rq < 4; ++rq) {
        f32x4 a, b2;
#pragma unroll
        for (int j = 0; j < 4; ++j) { a[j] = o0[rq * 4 + j]; b2[j] = o1[rq * 4 + j]; }
        *(f32x4*)&Ob[row * 64 + rq * 8 + 4 * h] = a;
        *(f32x4*)&Ob[row * 64 + 32 + rq * 8 + 4 * h] = b2;
    }
    if (l < 32) ml[(size_t)part * 128 + (w * 32 + l)] = lrun;
}

// ---------- kernel 5: split-K combine (static shift -> exact add) ----------
__global__ __launch_bounds__(256) void combine(
    const float* __restrict__ Op, const float* __restrict__ ml,
    float* __restrict__ out) {
    const int tid = blockIdx.x * 256 + threadIdx.x;
    const int dg = tid & 15, gq = tid >> 4;
    const int bh = gq >> 11, s = gq & 2047;
    const int qb = s >> 7, q = s & 127;
    const int p0 = bh * 16 + qb, p1 = 512 + p0;

    const float l1 = ml[(size_t)p0 * 128 + q];
    const float l2 = ml[(size_t)p1 * 128 + q];
    const float inv = 1.0f / (l1 + l2);

    const f32x4 O1 = *(const f32x4*)&Op[(size_t)p0 * 8192 + q * 64 + dg * 4];
    const f32x4 O2 = *(const f32x4*)&Op[(size_t)p1 * 8192 + q * 64 + dg * 4];
    f32x4 r;
#pragma unroll
    for (int i = 0; i < 4; ++i) r[i] = (O1[i] + O2[i]) * inv;

    const int b = bh >> 4, hh = bh & 15;
    *(f32x4*)&out[((size_t)(b * SS + s)) * HID + hh * HD + dg * 4] = r;
}

// ---------- launch ----------
extern "C" void kernel_launch(void* const* d_in, const int* in_sizes, int n_in,
                              void* d_out, int out_size, void* d_ws, size_t ws_size,
                              hipStream_t stream) {
    (void)in_sizes; (void)n_in; (void)out_size; (void)ws_size;
    const float* hs  = (const float*)d_in[0];
    const float* msk = (const float*)d_in[1];
    const float* Wq  = (const float*)d_in[2];
    const float* bq  = (const float*)d_in[3];
    const float* Wk  = (const float*)d_in[4];
    const float* bk  = (const float*)d_in[5];
    const float* Wv  = (const float*)d_in[6];
    const float* bv  = (const float*)d_in[7];
    float* out = (float*)d_out;
    char* ws = (char*)d_ws;
    const size_t MB = 1 << 20;

    bf16* Qb  = (bf16*)ws;                    // 0..8MB   [B,H,S,D]
    bf16* Kb  = (bf16*)(ws + 8 * MB);         // 8..16
    bf16* Vb  = (bf16*)(ws + 16 * MB);        // 16..24
    float* mk2 = (float*)(ws + 24 * MB);      // 24MB + 16KB
    bf16* Xb  = (bf16*)(ws + 25 * MB);        // 25..33 (dead after gemm)
    bf16* Wt  = (bf16*)(ws + 33 * MB);        // 33..39 (dead after gemm)
    float* Opp = (float*)(ws + 25 * MB);      // 25..57 (aliases Xb/Wt)
    float* mlp = (float*)(ws + 59 * MB);      // 59..60

    cvt_hidden<<<dim3(MROW * HID / (256 * 8)), dim3(256), 0, stream>>>(hs, Xb);
    maskcvt<<<dim3(BB * SS / 256), dim3(256), 0, stream>>>(msk, mk2);
    wtrans<<<dim3(32, 32, 3), dim3(32, 8), 0, stream>>>(Wq, Wk, Wv, Wt);
    qkv_gemm<<<dim3(NQKV / 128, MROW / 128), dim3(256), 0, stream>>>(
        Xb, Wt, bq, bk, bv, Qb, Kb, Vb);
    attn_fwd<<<dim3(1024), dim3(256), 0, stream>>>(Qb, Kb, Vb, mk2, Opp, mlp);
    combine<<<dim3(4096), dim3(256), 0, stream>>>(Opp, mlp, out);
}

// Round 9
// 122.605 us; speedup vs baseline: 1.5312x; 1.2816x over previous
//
#include <hip/hip_runtime.h>
#include <cstdint>
#include <cstddef>

// ---------- types ----------
typedef __bf16 bf16;
typedef __attribute__((ext_vector_type(8))) __bf16 bf16x8;
typedef __attribute__((ext_vector_type(4))) float f32x4;
typedef __attribute__((ext_vector_type(16))) float f32x16;

#define MFMA16(a, b, c) __builtin_amdgcn_mfma_f32_16x16x32_bf16((a), (b), (c), 0, 0, 0)
#define MFMA32(a, b, c) __builtin_amdgcn_mfma_f32_32x32x16_bf16((a), (b), (c), 0, 0, 0)

// Problem constants (B=2, S=2048, HIDDEN=1024, H=16, D=64)
static constexpr int BB   = 2;
static constexpr int SS   = 2048;
static constexpr int HID  = 1024;
static constexpr int NH   = 16;
static constexpr int HD   = 64;
static constexpr int MROW = BB * SS;     // 4096
static constexpr int NQKV = 3 * HID;     // 3072
static constexpr float LOG2E = 1.4426950408889634f;
static constexpr float MSHIFT = 16.0f;   // static softmax shift (log2 domain)

// XOR swizzle on 16B slots
__device__ __forceinline__ int SW(int r) { return ((r ^ (r >> 3)) & 7) << 4; }

__device__ __forceinline__ uint32_t pack_bf16(float a, float b) {
    union { bf16 h[2]; uint32_t u; } x;
    x.h[0] = (bf16)a; x.h[1] = (bf16)b;
    return x.u;
}

__device__ __forceinline__ uint32_t pack_raw(bf16 a, bf16 b) {
    union { bf16 h[2]; uint32_t u; } x;
    x.h[0] = a; x.h[1] = b;
    return x.u;
}

__device__ __forceinline__ float exp2i(float x) {
    float r; asm("v_exp_f32 %0, %1" : "=v"(r) : "v"(x)); return r;
}

// v_permlane32_swap_b32: a' = [a.lo | b.lo], b' = [a.hi | b.hi]
__device__ __forceinline__ void plswap(uint32_t& a, uint32_t& b) {
    asm("v_permlane32_swap_b32 %0, %1" : "+v"(a), "+v"(b));
}

// async global->LDS, 16B per lane
__device__ __forceinline__ void gload16(const void* g, void* l) {
    __builtin_amdgcn_global_load_lds(
        (const __attribute__((address_space(1))) void*)g,
        (__attribute__((address_space(3))) void*)l, 16, 0, 0);
}

// ---------- kernel 1: fp32 -> bf16 convert ----------
__global__ __launch_bounds__(256) void cvt_hidden(const float* __restrict__ in,
                                                  bf16* __restrict__ out) {
    const int i = (blockIdx.x * 256 + threadIdx.x) * 8;
    float4 f0 = *(const float4*)&in[i];
    float4 f1 = *(const float4*)&in[i + 4];
    bf16x8 o;
    o[0] = (bf16)f0.x; o[1] = (bf16)f0.y; o[2] = (bf16)f0.z; o[3] = (bf16)f0.w;
    o[4] = (bf16)f1.x; o[5] = (bf16)f1.y; o[6] = (bf16)f1.z; o[7] = (bf16)f1.w;
    *(bf16x8*)&out[i] = o;
}

// ---------- kernel 1b: mask * log2e - MSHIFT ----------
__global__ __launch_bounds__(256) void maskcvt(const float* __restrict__ m,
                                               float* __restrict__ o) {
    const int i = blockIdx.x * 256 + threadIdx.x;
    o[i] = m[i] * LOG2E - MSHIFT;
}

// ---------- kernel 2: transpose-convert W -> Wt [n][k] bf16 ----------
__global__ __launch_bounds__(256) void wtrans(const float* __restrict__ Wq,
                                              const float* __restrict__ Wk,
                                              const float* __restrict__ Wv,
                                              bf16* __restrict__ Wt) {
    __shared__ float tile[32][33];
    const float* W = (blockIdx.z == 0) ? Wq : (blockIdx.z == 1) ? Wk : Wv;
    bf16* O = Wt + (size_t)blockIdx.z * HID * HID;
    const int x  = blockIdx.x * 32 + threadIdx.x;
    const int y0 = blockIdx.y * 32;
#pragma unroll
    for (int i = threadIdx.y; i < 32; i += 8)
        tile[i][threadIdx.x] = W[(size_t)(y0 + i) * HID + x];
    __syncthreads();
    const int k = y0 + threadIdx.x;
#pragma unroll
    for (int i = threadIdx.y; i < 32; i += 8)
        O[(size_t)(blockIdx.x * 32 + i) * HID + k] = (bf16)tile[threadIdx.x][i];
}

// ---------- kernel 3: QKV GEMM (global_load_lds staging; unchanged) ----------
__global__ __launch_bounds__(256) void qkv_gemm(
    const bf16* __restrict__ A, const bf16* __restrict__ Bt,
    const float* __restrict__ bq, const float* __restrict__ bk,
    const float* __restrict__ bv,
    bf16* __restrict__ Qo, bf16* __restrict__ Ko, bf16* __restrict__ Vo) {
    __shared__ __align__(16) bf16 As[128 * 32];
    __shared__ __align__(16) bf16 Bs[128 * 32];
    const int t = threadIdx.x, l = t & 63;
    const int l15 = l & 15, l4 = l >> 4;
    const int w = t >> 6;
    const int wm = w >> 1, wn = w & 1;
    const int m0 = blockIdx.y * 128, n0 = blockIdx.x * 128;

    f32x4 acc[4][4] = {};

    for (int kt = 0; kt < 32; ++kt) {
        const int k0 = kt * 32;
        __syncthreads();
#pragma unroll
        for (int cc = 0; cc < 2; ++cc) {
            const int c = t + cc * 256;
            const int row = c >> 2, col = (c & 3) * 8;
            gload16(&A[(size_t)(m0 + row) * HID + k0 + col], (char*)As + c * 16);
            gload16(&Bt[(size_t)(n0 + row) * HID + k0 + col], (char*)Bs + c * 16);
        }
        __syncthreads();

        bf16x8 af[4], bf_[4];
#pragma unroll
        for (int mi = 0; mi < 4; ++mi) {
            const int r = wm * 64 + mi * 16 + l15;
            af[mi] = *(const bf16x8*)((const char*)As + r * 64 + l4 * 16);
        }
#pragma unroll
        for (int ni = 0; ni < 4; ++ni) {
            const int r = wn * 64 + ni * 16 + l15;
            bf_[ni] = *(const bf16x8*)((const char*)Bs + r * 64 + l4 * 16);
        }
        __builtin_amdgcn_s_setprio(1);
#pragma unroll
        for (int mi = 0; mi < 4; ++mi)
#pragma unroll
            for (int ni = 0; ni < 4; ++ni)
                acc[mi][ni] = MFMA16(af[mi], bf_[ni], acc[mi][ni]);
        __builtin_amdgcn_s_setprio(0);
    }

#pragma unroll
    for (int mi = 0; mi < 4; ++mi) {
#pragma unroll
        for (int ni = 0; ni < 4; ++ni) {
            const int ng = n0 + wn * 64 + ni * 16 + l15;
            const int qkv = ng >> 10;
            const int nn = ng & 1023;
            const int hh = nn >> 6, dd = nn & 63;
            const float* bp = (qkv == 0) ? bq : (qkv == 1) ? bk : bv;
            bf16* op = (qkv == 0) ? Qo : (qkv == 1) ? Ko : Vo;
            const float bias = bp[nn];
            const float scl = (qkv == 0) ? 0.125f * LOG2E : 1.0f;
            const int mg = m0 + wm * 64 + mi * 16 + l4 * 4;
            const int bb = mg >> 11, ss = mg & 2047;
            bf16* dst = op + ((size_t)(bb * NH + hh) * SS + ss) * HD + dd;
#pragma unroll
            for (int j = 0; j < 4; ++j)
                dst[(size_t)j * HD] = (bf16)((acc[mi][ni][j] + bias) * scl);
        }
    }
}

// ---------- kernel 4: flash attention v9 ----------
// R6 base (85us) + two VALU cuts:
//  (1) mask folded into the MFMA C-operand (st initialized from mask' loads;
//      deletes 32 v_add per tile — the matrix pipe does the mask add),
//  (2) both 32-key groups' QK^T computed before softmax/PV (independent MFMA
//      cluster overlaps g0's exp/pack VALU burst; +16 VGPR only).
// Distinct LDS objects per buffer. Single barrier per tile, dbuf staging.
__global__ __launch_bounds__(256) void attn_fwd(
    const bf16* __restrict__ Q, const bf16* __restrict__ K,
    const bf16* __restrict__ V, const float* __restrict__ mkl,
    float* __restrict__ Op, float* __restrict__ ml) {
    __shared__ __align__(16) char Ks0[64 * 128];
    __shared__ __align__(16) char Ks1[64 * 128];
    __shared__ __align__(16) char Vt0[64 * 128];
    __shared__ __align__(16) char Vt1[64 * 128];

    const int t = threadIdx.x, l = t & 63, w = t >> 6;
    const int l31 = l & 31, h = l >> 5;

    const int bid = blockIdx.x;
    const int nid = (bid & 7) * 128 + (bid >> 3);   // 1024 = 8*128 bijective
    const int bh = nid >> 5, kh = (nid >> 4) & 1, qb = nid & 15;
    const int q0 = qb * 128 + w * 32;
    const int kbase = kh * (SS / 2);

    const bf16* Qp = Q + (size_t)bh * SS * HD;
    const bf16* Kp = K + (size_t)bh * SS * HD;
    const bf16* Vp = V + (size_t)bh * SS * HD;
    const float* mkp = mkl + (bh >> 4) * SS;

    // Q frags (B-operand): lane q = l31, d = c*16 + h*8 + e
    bf16x8 qf[4];
#pragma unroll
    for (int c = 0; c < 4; ++c)
        qf[c] = *(const bf16x8*)&Qp[(size_t)(q0 + l31) * HD + c * 16 + h * 8];

    float lrun = 0.f;
    f32x16 o0 = {}, o1 = {};   // O^T: rows d / d+32, col q = l31

    const int vp_ = t >> 3, vdb = (t & 7) * 8;

    // ---- staging helpers ----
    auto stageK = [&](int tile, char* dst) {
        const int key0 = kbase + tile * 64;
#pragma unroll
        for (int cc = 0; cc < 2; ++cc) {
            const int c = t + cc * 256;
            const int row = c >> 3;
            const int csw = (c & 7) ^ ((row ^ (row >> 3)) & 7);
            gload16(&Kp[(size_t)(key0 + row) * HD + csw * 8], dst + c * 16);
        }
    };
    auto loadV = [&](int tile, bf16x8& va, bf16x8& vb) {
        const int key0 = kbase + tile * 64;
        va = *(const bf16x8*)&Vp[(size_t)(key0 + 2 * vp_) * HD + vdb];
        vb = *(const bf16x8*)&Vp[(size_t)(key0 + 2 * vp_ + 1) * HD + vdb];
    };
    auto storeV = [&](char* Vtn, const bf16x8& va, const bf16x8& vb) {
#pragma unroll
        for (int i = 0; i < 8; ++i) {
            const int d = vdb + i;
            *(uint32_t*)(Vtn + d * 128 + ((vp_ * 4) ^ SW(d))) =
                pack_raw(va[i], vb[i]);
        }
    };

    // ---- prologue: stage tile 0 ----
    stageK(0, Ks0);
    {
        bf16x8 va, vb;
        loadV(0, va, vb);
        storeV(Vt0, va, vb);
    }
    __syncthreads();

    constexpr int NT = (SS / 2) / 64;   // 16
#pragma unroll 1
    for (int kt = 0; kt < NT; ++kt) {
        char* Ks = (kt & 1) ? Ks1 : Ks0;
        char* Vt = (kt & 1) ? Vt1 : Vt0;
        char* Ksn = (kt & 1) ? Ks0 : Ks1;
        char* Vtn = (kt & 1) ? Vt0 : Vt1;
        const int key0 = kbase + kt * 64;
        const bool more = (kt + 1) < NT;

        // ---- early-issue next tile staging ----
        bf16x8 va = {}, vb = {};
        if (more) {
            stageK(kt + 1, Ksn);
            loadV(kt + 1, va, vb);
        }

        // ---- QK^T both groups; C-operand = mask' (log2-domain additive) ----
        f32x16 s0, s1;
#pragma unroll
        for (int rq = 0; rq < 4; ++rq) {
            const f32x4 m0v = *(const f32x4*)&mkp[key0 + rq * 8 + 4 * h];
            const f32x4 m1v = *(const f32x4*)&mkp[key0 + 32 + rq * 8 + 4 * h];
#pragma unroll
            for (int j = 0; j < 4; ++j) {
                s0[rq * 4 + j] = m0v[j];
                s1[rq * 4 + j] = m1v[j];
            }
        }
        __builtin_amdgcn_s_setprio(1);
#pragma unroll
        for (int c = 0; c < 4; ++c) {
            const int r0 = l31;
            bf16x8 kf0 = *(const bf16x8*)(Ks + r0 * 128 +
                                          ((c * 32 + h * 16) ^ SW(r0)));
            s0 = MFMA32(kf0, qf[c], s0);
        }
#pragma unroll
        for (int c = 0; c < 4; ++c) {
            const int r1 = 32 + l31;
            bf16x8 kf1 = *(const bf16x8*)(Ks + r1 * 128 +
                                          ((c * 32 + h * 16) ^ SW(r1)));
            s1 = MFMA32(kf1, qf[c], s1);
        }
        __builtin_amdgcn_s_setprio(0);

        // ---- softmax + PV per group (static shift; p = 2^s) ----
#pragma unroll
        for (int g = 0; g < 2; ++g) {
            f32x16& st = g ? s1 : s0;
            float ps = 0.f;
#pragma unroll
            for (int r = 0; r < 16; ++r) {
                const float p = exp2i(st[r]);
                st[r] = p;
                ps += p;
            }
            lrun += ps;
#pragma unroll
            for (int cc = 0; cc < 2; ++cc) {
                uint32_t wA = pack_bf16(st[8 * cc + 0], st[8 * cc + 1]);
                uint32_t wB = pack_bf16(st[8 * cc + 2], st[8 * cc + 3]);
                uint32_t wC = pack_bf16(st[8 * cc + 4], st[8 * cc + 5]);
                uint32_t wD = pack_bf16(st[8 * cc + 6], st[8 * cc + 7]);
                plswap(wA, wC);
                plswap(wB, wD);
                union { uint32_t u[4]; bf16x8 v; } pb;
                pb.u[0] = wA; pb.u[1] = wB; pb.u[2] = wC; pb.u[3] = wD;
                const int colb = g * 64 + cc * 32 + h * 16;
                __builtin_amdgcn_s_setprio(1);
                {
                    bf16x8 vf0 = *(const bf16x8*)(Vt + l31 * 128 +
                                                  (colb ^ SW(l31)));
                    o0 = MFMA32(vf0, pb.v, o0);
                    const int r1 = 32 + l31;
                    bf16x8 vf1 = *(const bf16x8*)(Vt + r1 * 128 +
                                                  (colb ^ SW(r1)));
                    o1 = MFMA32(vf1, pb.v, o1);
                }
                __builtin_amdgcn_s_setprio(0);
            }
            // write next V tile mid-compute (after g0's PV)
            if (g == 0 && more) storeV(Vtn, va, vb);
        }
        __syncthreads();   // single barrier per tile
    }

    // ---- epilogue: partials ----
    lrun += __shfl_xor(lrun, 32);
    const int part = kh * 512 + bh * 16 + qb;
    float* Ob = Op + (size_t)part * 8192;
    const int row = w * 32 + l31;
#pragma unroll
    for (int rq = 0; rq < 4; ++rq) {
        f32x4 a, b2;
#pragma unroll
        for (int j = 0; j < 4; ++j) { a[j] = o0[rq * 4 + j]; b2[j] = o1[rq * 4 + j]; }
        *(f32x4*)&Ob[row * 64 + rq * 8 + 4 * h] = a;
        *(f32x4*)&Ob[row * 64 + 32 + rq * 8 + 4 * h] = b2;
    }
    if (l < 32) ml[(size_t)part * 128 + (w * 32 + l)] = lrun;
}

// ---------- kernel 5: split-K combine (static shift -> exact add) ----------
__global__ __launch_bounds__(256) void combine(
    const float* __restrict__ Op, const float* __restrict__ ml,
    float* __restrict__ out) {
    const int tid = blockIdx.x * 256 + threadIdx.x;
    const int dg = tid & 15, gq = tid >> 4;
    const int bh = gq >> 11, s = gq & 2047;
    const int qb = s >> 7, q = s & 127;
    const int p0 = bh * 16 + qb, p1 = 512 + p0;

    const float l1 = ml[(size_t)p0 * 128 + q];
    const float l2 = ml[(size_t)p1 * 128 + q];
    const float inv = 1.0f / (l1 + l2);

    const f32x4 O1 = *(const f32x4*)&Op[(size_t)p0 * 8192 + q * 64 + dg * 4];
    const f32x4 O2 = *(const f32x4*)&Op[(size_t)p1 * 8192 + q * 64 + dg * 4];
    f32x4 r;
#pragma unroll
    for (int i = 0; i < 4; ++i) r[i] = (O1[i] + O2[i]) * inv;

    const int b = bh >> 4, hh = bh & 15;
    *(f32x4*)&out[((size_t)(b * SS + s)) * HID + hh * HD + dg * 4] = r;
}

// ---------- launch ----------
extern "C" void kernel_launch(void* const* d_in, const int* in_sizes, int n_in,
                              void* d_out, int out_size, void* d_ws, size_t ws_size,
                              hipStream_t stream) {
    (void)in_sizes; (void)n_in; (void)out_size; (void)ws_size;
    const float* hs  = (const float*)d_in[0];
    const float* msk = (const float*)d_in[1];
    const float* Wq  = (const float*)d_in[2];
    const float* bq  = (const float*)d_in[3];
    const float* Wk  = (const float*)d_in[4];
    const float* bk  = (const float*)d_in[5];
    const float* Wv  = (const float*)d_in[6];
    const float* bv  = (const float*)d_in[7];
    float* out = (float*)d_out;
    char* ws = (char*)d_ws;
    const size_t MB = 1 << 20;

    bf16* Qb  = (bf16*)ws;                    // 0..8MB   [B,H,S,D]
    bf16* Kb  = (bf16*)(ws + 8 * MB);         // 8..16
    bf16* Vb  = (bf16*)(ws + 16 * MB);        // 16..24
    float* mk2 = (float*)(ws + 24 * MB);      // 24MB + 16KB
    bf16* Xb  = (bf16*)(ws + 25 * MB);        // 25..33 (dead after gemm)
    bf16* Wt  = (bf16*)(ws + 33 * MB);        // 33..39 (dead after gemm)
    float* Opp = (float*)(ws + 25 * MB);      // 25..57 (aliases Xb/Wt)
    float* mlp = (float*)(ws + 59 * MB);      // 59..60

    cvt_hidden<<<dim3(MROW * HID / (256 * 8)), dim3(256), 0, stream>>>(hs, Xb);
    maskcvt<<<dim3(BB * SS / 256), dim3(256), 0, stream>>>(msk, mk2);
    wtrans<<<dim3(32, 32, 3), dim3(32, 8), 0, stream>>>(Wq, Wk, Wv, Wt);
    qkv_gemm<<<dim3(NQKV / 128, MROW / 128), dim3(256), 0, stream>>>(
        Xb, Wt, bq, bk, bv, Qb, Kb, Vb);
    attn_fwd<<<dim3(1024), dim3(256), 0, stream>>>(Qb, Kb, Vb, mk2, Opp, mlp);
    combine<<<dim3(4096), dim3(256), 0, stream>>>(Opp, mlp, out);
}

// Round 10
// 120.081 us; speedup vs baseline: 1.5634x; 1.0210x over previous
//
#include <hip/hip_runtime.h>
#include <cstdint>
#include <cstddef>

// ---------- types ----------
typedef __bf16 bf16;
typedef _Float16 f16;
typedef __attribute__((ext_vector_type(8))) __bf16 bf16x8;
typedef __attribute__((ext_vector_type(4))) float f32x4;
typedef __attribute__((ext_vector_type(16))) float f32x16;
typedef __attribute__((ext_vector_type(4))) _Float16 f16x4;
typedef __attribute__((ext_vector_type(8))) _Float16 f16x8;

#define MFMA16(a, b, c) __builtin_amdgcn_mfma_f32_16x16x32_bf16((a), (b), (c), 0, 0, 0)
#define MFMA32(a, b, c) __builtin_amdgcn_mfma_f32_32x32x16_bf16((a), (b), (c), 0, 0, 0)

// Problem constants (B=2, S=2048, HIDDEN=1024, H=16, D=64)
static constexpr int BB   = 2;
static constexpr int SS   = 2048;
static constexpr int HID  = 1024;
static constexpr int NH   = 16;
static constexpr int HD   = 64;
static constexpr int MROW = BB * SS;     // 4096
static constexpr int NQKV = 3 * HID;     // 3072
static constexpr float LOG2E = 1.4426950408889634f;
static constexpr float MSHIFT = 16.0f;   // static softmax shift (log2 domain)

// XOR swizzle on 16B slots
__device__ __forceinline__ int SW(int r) { return ((r ^ (r >> 3)) & 7) << 4; }

__device__ __forceinline__ uint32_t pack_bf16(float a, float b) {
    union { bf16 h[2]; uint32_t u; } x;
    x.h[0] = (bf16)a; x.h[1] = (bf16)b;
    return x.u;
}

__device__ __forceinline__ uint32_t pack_raw(bf16 a, bf16 b) {
    union { bf16 h[2]; uint32_t u; } x;
    x.h[0] = a; x.h[1] = b;
    return x.u;
}

__device__ __forceinline__ float exp2i(float x) {
    float r; asm("v_exp_f32 %0, %1" : "=v"(r) : "v"(x)); return r;
}

// v_permlane32_swap_b32: a' = [a.lo | b.lo], b' = [a.hi | b.hi]
__device__ __forceinline__ void plswap(uint32_t& a, uint32_t& b) {
    asm("v_permlane32_swap_b32 %0, %1" : "+v"(a), "+v"(b));
}

// async global->LDS, 16B per lane
__device__ __forceinline__ void gload16(const void* g, void* l) {
    __builtin_amdgcn_global_load_lds(
        (const __attribute__((address_space(1))) void*)g,
        (__attribute__((address_space(3))) void*)l, 16, 0, 0);
}

// ---------- kernel 1: fp32 -> bf16 convert ----------
__global__ __launch_bounds__(256) void cvt_hidden(const float* __restrict__ in,
                                                  bf16* __restrict__ out) {
    const int i = (blockIdx.x * 256 + threadIdx.x) * 8;
    float4 f0 = *(const float4*)&in[i];
    float4 f1 = *(const float4*)&in[i + 4];
    bf16x8 o;
    o[0] = (bf16)f0.x; o[1] = (bf16)f0.y; o[2] = (bf16)f0.z; o[3] = (bf16)f0.w;
    o[4] = (bf16)f1.x; o[5] = (bf16)f1.y; o[6] = (bf16)f1.z; o[7] = (bf16)f1.w;
    *(bf16x8*)&out[i] = o;
}

// ---------- kernel 1b: mask * log2e - MSHIFT ----------
__global__ __launch_bounds__(256) void maskcvt(const float* __restrict__ m,
                                               float* __restrict__ o) {
    const int i = blockIdx.x * 256 + threadIdx.x;
    o[i] = m[i] * LOG2E - MSHIFT;
}

// ---------- kernel 2: transpose-convert W -> Wt [n][k] bf16 ----------
__global__ __launch_bounds__(256) void wtrans(const float* __restrict__ Wq,
                                              const float* __restrict__ Wk,
                                              const float* __restrict__ Wv,
                                              bf16* __restrict__ Wt) {
    __shared__ float tile[32][33];
    const float* W = (blockIdx.z == 0) ? Wq : (blockIdx.z == 1) ? Wk : Wv;
    bf16* O = Wt + (size_t)blockIdx.z * HID * HID;
    const int x  = blockIdx.x * 32 + threadIdx.x;
    const int y0 = blockIdx.y * 32;
#pragma unroll
    for (int i = threadIdx.y; i < 32; i += 8)
        tile[i][threadIdx.x] = W[(size_t)(y0 + i) * HID + x];
    __syncthreads();
    const int k = y0 + threadIdx.x;
#pragma unroll
    for (int i = threadIdx.y; i < 32; i += 8)
        O[(size_t)(blockIdx.x * 32 + i) * HID + k] = (bf16)tile[threadIdx.x][i];
}

// ---------- kernel 3: QKV GEMM (global_load_lds staging; unchanged) ----------
__global__ __launch_bounds__(256) void qkv_gemm(
    const bf16* __restrict__ A, const bf16* __restrict__ Bt,
    const float* __restrict__ bq, const float* __restrict__ bk,
    const float* __restrict__ bv,
    bf16* __restrict__ Qo, bf16* __restrict__ Ko, bf16* __restrict__ Vo) {
    __shared__ __align__(16) bf16 As[128 * 32];
    __shared__ __align__(16) bf16 Bs[128 * 32];
    const int t = threadIdx.x, l = t & 63;
    const int l15 = l & 15, l4 = l >> 4;
    const int w = t >> 6;
    const int wm = w >> 1, wn = w & 1;
    const int m0 = blockIdx.y * 128, n0 = blockIdx.x * 128;

    f32x4 acc[4][4] = {};

    for (int kt = 0; kt < 32; ++kt) {
        const int k0 = kt * 32;
        __syncthreads();
#pragma unroll
        for (int cc = 0; cc < 2; ++cc) {
            const int c = t + cc * 256;
            const int row = c >> 2, col = (c & 3) * 8;
            gload16(&A[(size_t)(m0 + row) * HID + k0 + col], (char*)As + c * 16);
            gload16(&Bt[(size_t)(n0 + row) * HID + k0 + col], (char*)Bs + c * 16);
        }
        __syncthreads();

        bf16x8 af[4], bf_[4];
#pragma unroll
        for (int mi = 0; mi < 4; ++mi) {
            const int r = wm * 64 + mi * 16 + l15;
            af[mi] = *(const bf16x8*)((const char*)As + r * 64 + l4 * 16);
        }
#pragma unroll
        for (int ni = 0; ni < 4; ++ni) {
            const int r = wn * 64 + ni * 16 + l15;
            bf_[ni] = *(const bf16x8*)((const char*)Bs + r * 64 + l4 * 16);
        }
        __builtin_amdgcn_s_setprio(1);
#pragma unroll
        for (int mi = 0; mi < 4; ++mi)
#pragma unroll
            for (int ni = 0; ni < 4; ++ni)
                acc[mi][ni] = MFMA16(af[mi], bf_[ni], acc[mi][ni]);
        __builtin_amdgcn_s_setprio(0);
    }

#pragma unroll
    for (int mi = 0; mi < 4; ++mi) {
#pragma unroll
        for (int ni = 0; ni < 4; ++ni) {
            const int ng = n0 + wn * 64 + ni * 16 + l15;
            const int qkv = ng >> 10;
            const int nn = ng & 1023;
            const int hh = nn >> 6, dd = nn & 63;
            const float* bp = (qkv == 0) ? bq : (qkv == 1) ? bk : bv;
            bf16* op = (qkv == 0) ? Qo : (qkv == 1) ? Ko : Vo;
            const float bias = bp[nn];
            const float scl = (qkv == 0) ? 0.125f * LOG2E : 1.0f;
            const int mg = m0 + wm * 64 + mi * 16 + l4 * 4;
            const int bb = mg >> 11, ss = mg & 2047;
            bf16* dst = op + ((size_t)(bb * NH + hh) * SS + ss) * HD + dd;
#pragma unroll
            for (int j = 0; j < 4; ++j)
                dst[(size_t)j * HD] = (bf16)((acc[mi][ni][j] + bias) * scl);
        }
    }
}

// ---------- kernel 4: flash attention v10 ----------
// R9 base (72us, prediction-validated) + two cuts:
//  (1) row-sum via ones-MFMA: o2 = MFMA32(ones, pb, o2) replaces the 32-add
//      ps chain AND the epilogue shfl (l = o2[any row], covers all keys).
//      l now sums bf16-rounded p — consistent with the PV numerator.
//  (2) split-K partials stored as f16 (halves partial traffic).
__global__ __launch_bounds__(256) void attn_fwd(
    const bf16* __restrict__ Q, const bf16* __restrict__ K,
    const bf16* __restrict__ V, const float* __restrict__ mkl,
    f16* __restrict__ Op, float* __restrict__ ml) {
    __shared__ __align__(16) char Ks0[64 * 128];
    __shared__ __align__(16) char Ks1[64 * 128];
    __shared__ __align__(16) char Vt0[64 * 128];
    __shared__ __align__(16) char Vt1[64 * 128];

    const int t = threadIdx.x, l = t & 63, w = t >> 6;
    const int l31 = l & 31, h = l >> 5;

    const int bid = blockIdx.x;
    const int nid = (bid & 7) * 128 + (bid >> 3);   // 1024 = 8*128 bijective
    const int bh = nid >> 5, kh = (nid >> 4) & 1, qb = nid & 15;
    const int q0 = qb * 128 + w * 32;
    const int kbase = kh * (SS / 2);

    const bf16* Qp = Q + (size_t)bh * SS * HD;
    const bf16* Kp = K + (size_t)bh * SS * HD;
    const bf16* Vp = V + (size_t)bh * SS * HD;
    const float* mkp = mkl + (bh >> 4) * SS;

    // Q frags (B-operand): lane q = l31, d = c*16 + h*8 + e
    bf16x8 qf[4];
#pragma unroll
    for (int c = 0; c < 4; ++c)
        qf[c] = *(const bf16x8*)&Qp[(size_t)(q0 + l31) * HD + c * 16 + h * 8];

    // ones A-fragment for the row-sum MFMA
    bf16x8 ones;
#pragma unroll
    for (int i = 0; i < 8; ++i) ones[i] = (bf16)1.0f;

    f32x16 o0 = {}, o1 = {};   // O^T: rows d / d+32, col q = l31
    f32x16 o2 = {};            // row-sum accumulator (all rows = sum_k P[k][q])

    const int vp_ = t >> 3, vdb = (t & 7) * 8;

    // ---- staging helpers ----
    auto stageK = [&](int tile, char* dst) {
        const int key0 = kbase + tile * 64;
#pragma unroll
        for (int cc = 0; cc < 2; ++cc) {
            const int c = t + cc * 256;
            const int row = c >> 3;
            const int csw = (c & 7) ^ ((row ^ (row >> 3)) & 7);
            gload16(&Kp[(size_t)(key0 + row) * HD + csw * 8], dst + c * 16);
        }
    };
    auto loadV = [&](int tile, bf16x8& va, bf16x8& vb) {
        const int key0 = kbase + tile * 64;
        va = *(const bf16x8*)&Vp[(size_t)(key0 + 2 * vp_) * HD + vdb];
        vb = *(const bf16x8*)&Vp[(size_t)(key0 + 2 * vp_ + 1) * HD + vdb];
    };
    auto storeV = [&](char* Vtn, const bf16x8& va, const bf16x8& vb) {
#pragma unroll
        for (int i = 0; i < 8; ++i) {
            const int d = vdb + i;
            *(uint32_t*)(Vtn + d * 128 + ((vp_ * 4) ^ SW(d))) =
                pack_raw(va[i], vb[i]);
        }
    };

    // ---- prologue: stage tile 0 ----
    stageK(0, Ks0);
    {
        bf16x8 va, vb;
        loadV(0, va, vb);
        storeV(Vt0, va, vb);
    }
    __syncthreads();

    constexpr int NT = (SS / 2) / 64;   // 16
#pragma unroll 1
    for (int kt = 0; kt < NT; ++kt) {
        char* Ks = (kt & 1) ? Ks1 : Ks0;
        char* Vt = (kt & 1) ? Vt1 : Vt0;
        char* Ksn = (kt & 1) ? Ks0 : Ks1;
        char* Vtn = (kt & 1) ? Vt0 : Vt1;
        const int key0 = kbase + kt * 64;
        const bool more = (kt + 1) < NT;

        // ---- early-issue next tile staging ----
        bf16x8 va = {}, vb = {};
        if (more) {
            stageK(kt + 1, Ksn);
            loadV(kt + 1, va, vb);
        }

        // ---- QK^T both groups; C-operand = mask' (log2-domain additive) ----
        f32x16 s0, s1;
#pragma unroll
        for (int rq = 0; rq < 4; ++rq) {
            const f32x4 m0v = *(const f32x4*)&mkp[key0 + rq * 8 + 4 * h];
            const f32x4 m1v = *(const f32x4*)&mkp[key0 + 32 + rq * 8 + 4 * h];
#pragma unroll
            for (int j = 0; j < 4; ++j) {
                s0[rq * 4 + j] = m0v[j];
                s1[rq * 4 + j] = m1v[j];
            }
        }
        __builtin_amdgcn_s_setprio(1);
#pragma unroll
        for (int c = 0; c < 4; ++c) {
            const int r0 = l31;
            bf16x8 kf0 = *(const bf16x8*)(Ks + r0 * 128 +
                                          ((c * 32 + h * 16) ^ SW(r0)));
            s0 = MFMA32(kf0, qf[c], s0);
        }
#pragma unroll
        for (int c = 0; c < 4; ++c) {
            const int r1 = 32 + l31;
            bf16x8 kf1 = *(const bf16x8*)(Ks + r1 * 128 +
                                          ((c * 32 + h * 16) ^ SW(r1)));
            s1 = MFMA32(kf1, qf[c], s1);
        }
        __builtin_amdgcn_s_setprio(0);

        // ---- softmax + PV per group (static shift; p = 2^s; sum via MFMA) --
#pragma unroll
        for (int g = 0; g < 2; ++g) {
            f32x16& st = g ? s1 : s0;
#pragma unroll
            for (int r = 0; r < 16; ++r) st[r] = exp2i(st[r]);
#pragma unroll
            for (int cc = 0; cc < 2; ++cc) {
                uint32_t wA = pack_bf16(st[8 * cc + 0], st[8 * cc + 1]);
                uint32_t wB = pack_bf16(st[8 * cc + 2], st[8 * cc + 3]);
                uint32_t wC = pack_bf16(st[8 * cc + 4], st[8 * cc + 5]);
                uint32_t wD = pack_bf16(st[8 * cc + 6], st[8 * cc + 7]);
                plswap(wA, wC);
                plswap(wB, wD);
                union { uint32_t u[4]; bf16x8 v; } pb;
                pb.u[0] = wA; pb.u[1] = wB; pb.u[2] = wC; pb.u[3] = wD;
                const int colb = g * 64 + cc * 32 + h * 16;
                __builtin_amdgcn_s_setprio(1);
                {
                    o2 = MFMA32(ones, pb.v, o2);     // row-sum on matrix pipe
                    bf16x8 vf0 = *(const bf16x8*)(Vt + l31 * 128 +
                                                  (colb ^ SW(l31)));
                    o0 = MFMA32(vf0, pb.v, o0);
                    const int r1 = 32 + l31;
                    bf16x8 vf1 = *(const bf16x8*)(Vt + r1 * 128 +
                                                  (colb ^ SW(r1)));
                    o1 = MFMA32(vf1, pb.v, o1);
                }
                __builtin_amdgcn_s_setprio(0);
            }
            // write next V tile mid-compute (after g0's PV)
            if (g == 0 && more) storeV(Vtn, va, vb);
        }
        __syncthreads();   // single barrier per tile
    }

    // ---- epilogue: f16 partials; l from o2 (all rows equal, full key range) --
    const int part = kh * 512 + bh * 16 + qb;
    f16* Ob = Op + (size_t)part * 8192;
    const int row = w * 32 + l31;
#pragma unroll
    for (int rq = 0; rq < 4; ++rq) {
        f16x4 a, b2;
#pragma unroll
        for (int j = 0; j < 4; ++j) {
            a[j]  = (f16)o0[rq * 4 + j];
            b2[j] = (f16)o1[rq * 4 + j];
        }
        *(f16x4*)&Ob[row * 64 + rq * 8 + 4 * h] = a;
        *(f16x4*)&Ob[row * 64 + 32 + rq * 8 + 4 * h] = b2;
    }
    if (l < 32) ml[(size_t)part * 128 + (w * 32 + l)] = o2[0];
}

// ---------- kernel 5: split-K combine (f16 partials, 8-d per thread) ----------
__global__ __launch_bounds__(256) void combine(
    const f16* __restrict__ Op, const float* __restrict__ ml,
    float* __restrict__ out) {
    const int tid = blockIdx.x * 256 + threadIdx.x;
    const int dg = tid & 7, gq = tid >> 3;
    const int bh = gq >> 11, s = gq & 2047;
    const int qb = s >> 7, q = s & 127;
    const int p0 = bh * 16 + qb, p1 = 512 + p0;

    const float l1 = ml[(size_t)p0 * 128 + q];
    const float l2 = ml[(size_t)p1 * 128 + q];
    const float inv = 1.0f / (l1 + l2);

    const f16x8 O1 = *(const f16x8*)&Op[(size_t)p0 * 8192 + q * 64 + dg * 8];
    const f16x8 O2 = *(const f16x8*)&Op[(size_t)p1 * 8192 + q * 64 + dg * 8];
    f32x4 r0, r1;
#pragma unroll
    for (int i = 0; i < 4; ++i) {
        r0[i] = ((float)O1[i] + (float)O2[i]) * inv;
        r1[i] = ((float)O1[4 + i] + (float)O2[4 + i]) * inv;
    }

    const int b = bh >> 4, hh = bh & 15;
    float* op = &out[((size_t)(b * SS + s)) * HID + hh * HD + dg * 8];
    *(f32x4*)op = r0;
    *(f32x4*)(op + 4) = r1;
}

// ---------- launch ----------
extern "C" void kernel_launch(void* const* d_in, const int* in_sizes, int n_in,
                              void* d_out, int out_size, void* d_ws, size_t ws_size,
                              hipStream_t stream) {
    (void)in_sizes; (void)n_in; (void)out_size; (void)ws_size;
    const float* hs  = (const float*)d_in[0];
    const float* msk = (const float*)d_in[1];
    const float* Wq  = (const float*)d_in[2];
    const float* bq  = (const float*)d_in[3];
    const float* Wk  = (const float*)d_in[4];
    const float* bk  = (const float*)d_in[5];
    const float* Wv  = (const float*)d_in[6];
    const float* bv  = (const float*)d_in[7];
    float* out = (float*)d_out;
    char* ws = (char*)d_ws;
    const size_t MB = 1 << 20;

    bf16* Qb  = (bf16*)ws;                    // 0..8MB   [B,H,S,D]
    bf16* Kb  = (bf16*)(ws + 8 * MB);         // 8..16
    bf16* Vb  = (bf16*)(ws + 16 * MB);        // 16..24
    float* mk2 = (float*)(ws + 24 * MB);      // 24MB + 16KB
    bf16* Xb  = (bf16*)(ws + 25 * MB);        // 25..33 (dead after gemm)
    bf16* Wt  = (bf16*)(ws + 33 * MB);        // 33..39 (dead after gemm)
    f16* Opp  = (f16*)(ws + 25 * MB);         // 25..41 (aliases Xb/Wt, 16MB)
    float* mlp = (float*)(ws + 59 * MB);      // 59..60

    cvt_hidden<<<dim3(MROW * HID / (256 * 8)), dim3(256), 0, stream>>>(hs, Xb);
    maskcvt<<<dim3(BB * SS / 256), dim3(256), 0, stream>>>(msk, mk2);
    wtrans<<<dim3(32, 32, 3), dim3(32, 8), 0, stream>>>(Wq, Wk, Wv, Wt);
    qkv_gemm<<<dim3(NQKV / 128, MROW / 128), dim3(256), 0, stream>>>(
        Xb, Wt, bq, bk, bv, Qb, Kb, Vb);
    attn_fwd<<<dim3(1024), dim3(256), 0, stream>>>(Qb, Kb, Vb, mk2, Opp, mlp);
    combine<<<dim3(2048), dim3(256), 0, stream>>>(Opp, mlp, out);
}